// Round 1
// 2266.063 us; speedup vs baseline: 5.4447x; 5.4447x over previous
//
#include <hip/hip_runtime.h>

typedef unsigned short u16;
typedef unsigned int   u32;
using short8  = __attribute__((ext_vector_type(8))) short;
using short4v = __attribute__((ext_vector_type(4))) short;
using f32x4   = __attribute__((ext_vector_type(4))) float;
using f32x2   = __attribute__((ext_vector_type(2))) float;

#define N_USER 200000
#define N_NEWS 100000
#define N_SRCT 5000
#define N_FOLW 200000
#define E_POSTS 500000
#define E_PUB   100000
#define E_FOLL  1000000
#define NCNT    805000            // total count entries across 6 relations
#define NPOOL   3200000           // total CSR pool entries (sum of E per relation)

__device__ __forceinline__ float bf2f(u16 h) {
  union { u32 u; float f; } v; v.u = ((u32)h) << 16; return v.f;
}
__device__ __forceinline__ u16 f2bf(float f) {
  union { float f; u32 u; } v; v.f = f;
  u32 r = v.u + 0x7FFFu + ((v.u >> 16) & 1u);
  return (u16)(r >> 16);
}

// ---------------- degree counting (into int array) ----------------
__global__ void count_k(const int* __restrict__ idx, int n, int* __restrict__ cnt) {
  int i = blockIdx.x * 256 + threadIdx.x;
  if (i < n) atomicAdd(&cnt[idx[i]], 1);
}
__global__ void rsqrt_k(const int* __restrict__ cnti, float* __restrict__ out, int n) {
  int i = blockIdx.x * 256 + threadIdx.x;
  if (i < n) {
    int c = cnti[i];
    out[i] = rsqrtf((float)(c > 0 ? c : 1));
  }
}

// ---------------- exclusive prefix scan over NCNT ints (3 kernels) ----------------
// scan1: per-block (256) inclusive scan -> out, block totals -> bsum
__global__ void scan1_k(const int* __restrict__ in, int* __restrict__ out,
                        int* __restrict__ bsum, int n) {
  __shared__ int s[256];
  int tid = threadIdx.x;
  int gid = blockIdx.x * 256 + tid;
  int v = (gid < n) ? in[gid] : 0;
  s[tid] = v;
  __syncthreads();
  for (int d = 1; d < 256; d <<= 1) {
    int t = (tid >= d) ? s[tid - d] : 0;
    __syncthreads();
    s[tid] += t;
    __syncthreads();
  }
  if (gid < n) out[gid] = s[tid];
  if (tid == 255) bsum[blockIdx.x] = s[255];
}
// scan2: single block, exclusive scan of bsum[m] in place (m <= 3328)
__global__ void scan2_k(int* __restrict__ bsum, int m) {
  __shared__ int p[256];
  __shared__ int buf[3328];
  int tid = threadIdx.x;
  int chunk = (m + 255) / 256;
  int run = 0;
  for (int i = 0; i < chunk; ++i) {
    int idx = tid * chunk + i;
    int v = (idx < m) ? bsum[idx] : 0;
    if (idx < m) buf[idx] = run;   // exclusive within chunk
    run += v;
  }
  p[tid] = run;
  __syncthreads();
  int own = run;
  for (int d = 1; d < 256; d <<= 1) {
    int t = (tid >= d) ? p[tid - d] : 0;
    __syncthreads();
    p[tid] += t;
    __syncthreads();
  }
  int base = p[tid] - own;         // exclusive across chunks
  for (int i = 0; i < chunk; ++i) {
    int idx = tid * chunk + i;
    if (idx < m) bsum[idx] = buf[idx] + base;
  }
}
// scan3: block-inclusive -> global exclusive: offs = offs - self + bsumExcl[block]
__global__ void scan3_k(int* __restrict__ offs, const int* __restrict__ cnti,
                        const int* __restrict__ bsum, int n) {
  int gid = blockIdx.x * 256 + threadIdx.x;
  if (gid < n) offs[gid] = offs[gid] - cnti[gid] + bsum[blockIdx.x];
}

// ---------------- CSR fill: pool[offs[d]+cursor++] = src[e] ----------------
__global__ void csr_fill_k(const int* __restrict__ src, const int* __restrict__ dst,
                           const int* __restrict__ offs, int* __restrict__ curs,
                           int* __restrict__ pool, int E, int cntOff) {
  int e = blockIdx.x * 256 + threadIdx.x;
  if (e >= E) return;
  int d = dst[e] + cntOff;
  int p = offs[d] + atomicAdd(&curs[d], 1);
  pool[p] = src[e];
}

// ---------------- fp32 -> bf16 convert + K-pad (row-major) ----------------
__global__ void cvt_pad_k(const float* __restrict__ X, u16* __restrict__ P,
                          int Ksrc, int Kdst, int total) {
  int i = blockIdx.x * 256 + threadIdx.x;
  if (i >= total) return;
  int row = i / Kdst;
  int k = i - row * Kdst;
  P[i] = (k < Ksrc) ? f2bf(X[(size_t)row * Ksrc + k]) : (u16)0;
}

// ---- weight: fp32 [nmat][Ksrc][128] -> bf16 k-major [nmat][128][Kdst] (K-padded) ----
__global__ void trans_w_k(const float* __restrict__ W, u16* __restrict__ WT,
                          int Ksrc, int Kdst, int total) {
  int i = blockIdx.x * 256 + threadIdx.x;
  if (i >= total) return;
  int per = Kdst << 7;
  int m = i / per, rem = i - m * per;
  int n = rem / Kdst, k = rem - n * Kdst;
  WT[i] = (k < Ksrc) ? f2bf(W[(size_t)m * Ksrc * 128 + (size_t)k * 128 + n]) : (u16)0;
}

// ---------------- MFMA GEMM: C[M,128] = act((A[M,K] @ W) * rowscale + bias) ----------------
__global__ __launch_bounds__(256, 2) void gemm_bf16(
    const u16* __restrict__ A, int lda, int M, int K,
    const u16* __restrict__ WT,
    const float* __restrict__ bias,     // 128 fp32 or null
    const float* __restrict__ rowscale, // M fp32 or null
    u16* __restrict__ C, int leaky)
{
  __shared__ u16 Ws[128][136];   // [n][k-chunk], +8 pad
  const int tid  = threadIdx.x;
  const int wave = tid >> 6;
  const int lane = tid & 63;
  const int l15  = lane & 15;
  const int l4   = lane >> 4;
  const int rowBase = blockIdx.x * 128 + wave * 32;

  f32x4 acc[2][8];
#pragma unroll
  for (int g = 0; g < 2; ++g)
#pragma unroll
    for (int c = 0; c < 8; ++c) acc[g][c] = (f32x4){0.f, 0.f, 0.f, 0.f};

  const int r0 = (rowBase + l15 < M) ? rowBase + l15 : M - 1;
  const int r1 = (rowBase + 16 + l15 < M) ? rowBase + 16 + l15 : M - 1;

  for (int kb = 0; kb < K; kb += 128) {
    const int chunkK = (K - kb < 128) ? (K - kb) : 128;
    __syncthreads();
    for (int fl = tid * 8; fl < (chunkK << 7); fl += 2048) {
      int n = fl / chunkK;
      int kk = fl - n * chunkK;
      *(short8*)(&Ws[n][kk]) = *(const short8*)(WT + (size_t)n * K + kb + kk);
    }
    __syncthreads();
    const int nsteps = chunkK >> 5;
    for (int ks = 0; ks < nsteps; ++ks) {
      const int kg = ks * 32 + l4 * 8;
      short8 a0 = *(const short8*)(A + (size_t)r0 * lda + kb + kg);
      short8 a1 = *(const short8*)(A + (size_t)r1 * lda + kb + kg);
#pragma unroll
      for (int c = 0; c < 8; ++c) {
        short8 b = *(const short8*)(&Ws[c * 16 + l15][kg]);
        acc[0][c] = __builtin_amdgcn_mfma_f32_16x16x32_bf16(a0, b, acc[0][c], 0, 0, 0);
        acc[1][c] = __builtin_amdgcn_mfma_f32_16x16x32_bf16(a1, b, acc[1][c], 0, 0, 0);
      }
    }
  }

  float bvals[8];
#pragma unroll
  for (int c = 0; c < 8; ++c) bvals[c] = bias ? bias[c * 16 + l15] : 0.f;

#pragma unroll
  for (int g = 0; g < 2; ++g) {
#pragma unroll
    for (int r = 0; r < 4; ++r) {
      int row = rowBase + g * 16 + l4 * 4 + r;
      if (row >= M) continue;
      float sc = rowscale ? rowscale[row] : 1.f;
#pragma unroll
      for (int c = 0; c < 8; ++c) {
        float v = acc[g][c][r] * sc + bvals[c];
        if (leaky) v = (v > 0.f) ? v : 0.01f * v;
        C[(size_t)row * 128 + c * 16 + l15] = f2bf(v);
      }
    }
  }
}

// ------- fused gather-aggregate + mean + bias + lrelu -------
// One wave per destination row; lane owns 2 columns (u32 = 2 bf16).
// out = lrelu( (sum_r rsqrt(deg_in_r)*sum_{e in CSR_r(d)} T_r[src_e]  + sum_r b_r) * invn )
__global__ __launch_bounds__(256) void gather_conv(
    const u16* __restrict__ T, const int* __restrict__ pool,
    const int* __restrict__ offs, const int* __restrict__ cnti,
    const float* __restrict__ rsin,
    int co0, int to0, int co1, int to1,
    const float* __restrict__ b1, const float* __restrict__ b2, float invn,
    u16* __restrict__ out_bf, float* __restrict__ out_f, int nDst)
{
  const int wave = threadIdx.x >> 6;
  const int lane = threadIdx.x & 63;
  const int d = blockIdx.x * 4 + wave;
  if (d >= nDst) return;

  float a0 = 0.f, a1 = 0.f;
  int co = co0, to = to0;
#pragma unroll 1
  for (int r = 0; r < 2; ++r) {
    if (co < 0) break;
    const int off = offs[co + d];
    const int cnt = cnti[co + d];
    float s0 = 0.f, s1 = 0.f;
    int e = 0;
    for (; e + 4 <= cnt; e += 4) {
      int i0 = pool[off + e];
      int i1 = pool[off + e + 1];
      int i2 = pool[off + e + 2];
      int i3 = pool[off + e + 3];
      u32 w0 = *(const u32*)(T + (((size_t)(to + i0)) << 7) + lane * 2);
      u32 w1 = *(const u32*)(T + (((size_t)(to + i1)) << 7) + lane * 2);
      u32 w2 = *(const u32*)(T + (((size_t)(to + i2)) << 7) + lane * 2);
      u32 w3 = *(const u32*)(T + (((size_t)(to + i3)) << 7) + lane * 2);
      s0 += bf2f((u16)w0) + bf2f((u16)w1) + bf2f((u16)w2) + bf2f((u16)w3);
      s1 += bf2f((u16)(w0 >> 16)) + bf2f((u16)(w1 >> 16)) +
            bf2f((u16)(w2 >> 16)) + bf2f((u16)(w3 >> 16));
    }
    for (; e < cnt; ++e) {
      int i0 = pool[off + e];
      u32 w0 = *(const u32*)(T + (((size_t)(to + i0)) << 7) + lane * 2);
      s0 += bf2f((u16)w0);
      s1 += bf2f((u16)(w0 >> 16));
    }
    const float sc = rsin[co + d];
    a0 += s0 * sc;
    a1 += s1 * sc;
    co = co1; to = to1;
  }

  const int col = lane * 2;
  const float bb0 = b1[col]     + (b2 ? b2[col]     : 0.f);
  const float bb1 = b1[col + 1] + (b2 ? b2[col + 1] : 0.f);
  float v0 = (a0 + bb0) * invn;
  float v1 = (a1 + bb1) * invn;
  v0 = (v0 > 0.f) ? v0 : 0.01f * v0;
  v1 = (v1 > 0.f) ? v1 : 0.01f * v1;
  if (out_f) {
    *(f32x2*)(out_f + (((size_t)d) << 7) + col) = (f32x2){v0, v1};
  } else {
    u32 pk = ((u32)f2bf(v1) << 16) | (u32)f2bf(v0);
    *(u32*)(out_bf + (((size_t)d) << 7) + col) = pk;
  }
}

// ---------------- final linear: [rows,128] @ [128,2] + b (all fp32) ----------------
__global__ __launch_bounds__(256) void linear_k(
    const float* __restrict__ H, const float* __restrict__ Wl,
    const float* __restrict__ bl, float* __restrict__ OUT, int rows)
{
  __shared__ float w0[128], w1[128];
  int tid = threadIdx.x;
  if (tid < 128) { w0[tid] = Wl[tid * 2]; w1[tid] = Wl[tid * 2 + 1]; }
  __syncthreads();
  int row = blockIdx.x * 256 + tid;
  if (row >= rows) return;
  const float* hp = H + ((size_t)row << 7);
  float s0 = 0.f, s1 = 0.f;
#pragma unroll
  for (int k = 0; k < 128; k += 4) {
    f32x4 h4 = *(const f32x4*)(hp + k);
#pragma unroll
    for (int j = 0; j < 4; ++j) {
      s0 += h4[j] * w0[k + j];
      s1 += h4[j] * w1[k + j];
    }
  }
  OUT[(size_t)row * 2]     = s0 + bl[0];
  OUT[(size_t)row * 2 + 1] = s1 + bl[1];
}

extern "C" void kernel_launch(void* const* d_in, const int* in_sizes, int n_in,
                              void* d_out, int out_size, void* d_ws, size_t ws_size,
                              hipStream_t stream)
{
  (void)in_sizes; (void)n_in; (void)out_size; (void)ws_size;

  // ---- workspace carve-up ----
  char* wp = (char*)d_ws;
  auto take = [&](size_t bytes) { void* p = wp; wp += (bytes + 255) & ~(size_t)255; return p; };
  u16*   ARENA = (u16*)take(206080000);  // first: XB bf16 inputs (167.7MB); later: T pool (206.1MB)
  u16*   HA  = (u16*)take(129280000);    // 505000*128 bf16
  u16*   HB  = (u16*)take(129280000);
  u16*   WTA = (u16*)take(1884160);      // transposed bf16 weights arena
  float* CNT = (float*)take(3220000);    // 805000 f32 rsqrt values
  int*   CNTI = (int*)take(3220000);     // 805000 int degree counts
  int*   OFFS = (int*)take(3220000);     // 805000 int CSR offsets (global exclusive scan)
  int*   CURS = (int*)take(3220000);     // 805000 int fill cursors
  int*   POOL = (int*)take(12800000);    // 3.2M int CSR src indices
  int*   BSUM = (int*)take(16384);       // scan block sums (3145)
  u16*   XB  = ARENA;                    // bf16 input arena — dead before T-pool use
  u16*   TP  = ARENA;                    // per-relation GEMM-output pool

  const int rowOff[4] = {0, 200000, 300000, 305000};   // user,news,source,follower
  const int Nt[4]     = {N_USER, N_NEWS, N_SRCT, N_FOLW};
  const size_t XOFF[4] = {0, 25600000, 57600000, 58240000};
  const int KD[4] = {128, 320, 128, 128};              // padded K per type
  const int KS[4] = {128, 300, 128, 128};
  const int WT1[4] = {0, 16384, 57344, 73728};
  const int WT2 = 90112, WTC1 = 155648, WTC2 = 548864;

  // relation table: E, src idx, dst idx, src type, dst type, srcCnt off, dstCnt off, T-row off
  struct RelG { int E, srcIdx, dstIdx, srcType, dstType, srcCnt, dstCnt, tOff; };
  const RelG rels[6] = {
    {E_POSTS, 26, 27, 0, 1, 0,      200000, 0},       // posts: user->news
    {E_POSTS, 27, 26, 1, 0, 200000, 0,      200000},  // posted_by: news->user
    {E_PUB,   28, 29, 2, 1, 300000, 305000, 300000},  // publishes: source->news
    {E_PUB,   29, 28, 1, 2, 305000, 300000, 305000},  // published_by: news->source
    {E_FOLL,  30, 31, 3, 0, 405000, 605000, 405000},  // follows: follower->user
    {E_FOLL,  31, 30, 0, 3, 605000, 405000, 605000},  // followed_by: user->follower
  };

  // ---- degrees (int) ----
  hipMemsetAsync(CNTI, 0, NCNT * 4, stream);
  for (int r = 0; r < 6; ++r) {
    // count over the relation's src array (out-degree region) — note each region is
    // counted exactly once across the 6 launches below.
  }
  count_k<<<(E_POSTS + 255) / 256, 256, 0, stream>>>((const int*)d_in[26], E_POSTS, CNTI + 0);
  count_k<<<(E_POSTS + 255) / 256, 256, 0, stream>>>((const int*)d_in[27], E_POSTS, CNTI + 200000);
  count_k<<<(E_PUB   + 255) / 256, 256, 0, stream>>>((const int*)d_in[28], E_PUB,   CNTI + 300000);
  count_k<<<(E_PUB   + 255) / 256, 256, 0, stream>>>((const int*)d_in[29], E_PUB,   CNTI + 305000);
  count_k<<<(E_FOLL  + 255) / 256, 256, 0, stream>>>((const int*)d_in[30], E_FOLL,  CNTI + 405000);
  count_k<<<(E_FOLL  + 255) / 256, 256, 0, stream>>>((const int*)d_in[31], E_FOLL,  CNTI + 605000);
  rsqrt_k<<<(NCNT + 255) / 256, 256, 0, stream>>>(CNTI, CNT, NCNT);

  // ---- CSR build (once; graph static across layers) ----
  const int scanBlocks = (NCNT + 255) / 256;   // 3145
  scan1_k<<<scanBlocks, 256, 0, stream>>>(CNTI, OFFS, BSUM, NCNT);
  scan2_k<<<1, 256, 0, stream>>>(BSUM, scanBlocks);
  scan3_k<<<scanBlocks, 256, 0, stream>>>(OFFS, CNTI, BSUM, NCNT);
  hipMemsetAsync(CURS, 0, NCNT * 4, stream);
  for (int r = 0; r < 6; ++r) {
    csr_fill_k<<<(rels[r].E + 255) / 256, 256, 0, stream>>>(
        (const int*)d_in[rels[r].srcIdx], (const int*)d_in[rels[r].dstIdx],
        OFFS, CURS, POOL, rels[r].E, rels[r].dstCnt);
  }

  // ---- convert inputs fp32->bf16 (+pad news K 300->320) into XB ----
  for (int t = 0; t < 4; ++t) {
    int total = Nt[t] * KD[t];
    cvt_pad_k<<<(total + 255) / 256, 256, 0, stream>>>(
        (const float*)d_in[t], XB + XOFF[t], KS[t], KD[t], total);
  }
  // ---- weights fp32 -> bf16 k-major (+pad news Wi1) ----
  auto transL = [&](int idx, int wtOff, int Ksrc, int Kdst, int total) {
    trans_w_k<<<(total + 255) / 256, 256, 0, stream>>>(
        (const float*)d_in[idx], WTA + wtOff, Ksrc, Kdst, total);
  };
  transL(4,  WT1[0], 128, 128, 16384);
  transL(6,  WT1[1], 300, 320, 40960);
  transL(8,  WT1[2], 128, 128, 16384);
  transL(10, WT1[3], 128, 128, 16384);
  transL(12, WT2,    128, 128, 65536);    // Wi2 (4 mats)
  transL(14, WTC1,   128, 128, 393216);   // conv1_W (24 mats)
  transL(16, WTC2,   128, 128, 393216);   // conv2_W (24 mats)

  auto gemmL = [&](const u16* A, int lda, int M, int K, const u16* WTp,
                   const float* bias, const float* rs, u16* C, int leaky) {
    gemm_bf16<<<(M + 127) / 128, 256, 0, stream>>>(A, lda, M, K, WTp, bias, rs, C, leaky);
  };

  // ---- stage1: h = lrelu(x @ Wi1 + bi1) -> HA ----
  for (int t = 0; t < 4; ++t)
    gemmL(XB + XOFF[t], KD[t], Nt[t], KD[t], WTA + WT1[t],
          (const float*)d_in[5 + 2 * t], nullptr, HA + (size_t)rowOff[t] * 128, 1);

  // ---- stage2: h = lrelu(h @ Wi2 + bi2) -> HB ----
  for (int t = 0; t < 4; ++t)
    gemmL(HA + (size_t)rowOff[t] * 128, 128, Nt[t], 128, WTA + WT2 + t * 16384,
          (const float*)d_in[13] + t * 128, nullptr, HB + (size_t)rowOff[t] * 128, 1);

  const size_t H1OFF[4] = {1010000, 26610000, 39410000, 40050000};
  const size_t LOFF[4]  = {0, 400000, 600000, 610000};
  const int relsOf[4][2] = {{1, 4}, {0, 2}, {3, -1}, {5, -1}};
  float* OUT = (float*)d_out;

  // ---- conv layers (XB dead from here; T pool takes over ARENA) ----
  for (int layer = 0; layer < 2; ++layer) {
    const u16* HIn     = layer ? HA : HB;
    const u16* wt      = WTA + (layer ? WTC2 : WTC1);
    const float* convb = (const float*)d_in[layer ? 17 : 15];
    // T_r = (h_src * rsqrt(deg_out)) @ W[dstType][r]  (row-scale commutes with @W)
    for (int r = 0; r < 6; ++r) {
      const RelG& q = rels[r];
      gemmL(HIn + (size_t)rowOff[q.srcType] * 128, 128, Nt[q.srcType], 128,
            wt + (size_t)(q.dstType * 6 + r) * 16384, nullptr, CNT + q.srcCnt,
            TP + (size_t)q.tOff * 128, 0);
    }
    // fused gather + mean + bias + lrelu per dst type
    for (int k = 0; k < 4; ++k) {
      int r1 = relsOf[k][0], r2 = relsOf[k][1];
      int co0 = rels[r1].dstCnt, to0 = rels[r1].tOff;
      int co1 = (r2 >= 0) ? rels[r2].dstCnt : -1;
      int to1 = (r2 >= 0) ? rels[r2].tOff : 0;
      const float* b1 = convb + (size_t)(k * 6 + r1) * 128;
      const float* b2 = (r2 >= 0) ? convb + (size_t)(k * 6 + r2) * 128 : nullptr;
      float invn = (r2 >= 0) ? 0.5f : 1.0f;
      u16* obf  = layer ? nullptr : (HA + (size_t)rowOff[k] * 128);
      float* of = layer ? (OUT + H1OFF[k]) : nullptr;
      gather_conv<<<(Nt[k] + 3) / 4, 256, 0, stream>>>(
          TP, POOL, OFFS, CNTI, CNT, co0, to0, co1, to1, b1, b2, invn, obf, of, Nt[k]);
    }
  }

  // ---- final linear: logits = h1 @ Wl + bl ----
  for (int k = 0; k < 4; ++k)
    linear_k<<<(Nt[k] + 255) / 256, 256, 0, stream>>>(
        OUT + H1OFF[k], (const float*)d_in[18 + 2 * k], (const float*)d_in[19 + 2 * k],
        OUT + LOFF[k], Nt[k]);
}